// Round 1
// baseline (1612.832 us; speedup 1.0000x reference)
//
#include <hip/hip_runtime.h>

#define N_TOTAL 60000
#define N_X     50000
#define N_EDGE  1920000
#define NFEAT   512
#define NHID    256

// ---------------- Dense GEMM: C[M x 256] = A[M x K] @ W[K x 256] ----------------
// A may be a concat of two buffers (layer 1): rows < split come from A, rest from A2.
#define BM 64
#define BN 64
#define BK 16

__global__ __launch_bounds__(256)
void gemm_kernel(const float* __restrict__ A, const float* __restrict__ A2, int split,
                 const float* __restrict__ W, float* __restrict__ C, int M, int K)
{
    __shared__ float As[BK][BM + 4];   // +4 keeps float4 alignment (68*4B = 272B, 16B-aligned rows)
    __shared__ float Bs[BK][BN];
    const int t  = threadIdx.x;
    const int tx = t & 15;    // column group (4 cols each)
    const int ty = t >> 4;    // row group (4 rows each)
    const int bm = blockIdx.x * BM;
    const int bn = blockIdx.y * BN;

    float acc[4][4] = {};

    for (int kk = 0; kk < K; kk += BK) {
        // A tile: 64 rows x 16 k  (one float4 per thread), stored transposed As[k][m]
        {
            int m  = t >> 2;
            int k4 = t & 3;
            int row = bm + m;
            float4 v = make_float4(0.f, 0.f, 0.f, 0.f);
            if (row < M) {
                const float* src = (row < split) ? (A + (size_t)row * K)
                                                 : (A2 + (size_t)(row - split) * K);
                v = *(const float4*)(src + kk + k4 * 4);
            }
            As[k4 * 4 + 0][m] = v.x;
            As[k4 * 4 + 1][m] = v.y;
            As[k4 * 4 + 2][m] = v.z;
            As[k4 * 4 + 3][m] = v.w;
        }
        // B tile: 16 k x 64 n (one float4 per thread)
        {
            int k  = t >> 4;
            int n4 = t & 15;
            float4 v = *(const float4*)(W + (size_t)(kk + k) * NHID + bn + n4 * 4);
            *(float4*)&Bs[k][n4 * 4] = v;
        }
        __syncthreads();
        #pragma unroll
        for (int k = 0; k < BK; k++) {
            float4 a = *(const float4*)&As[k][ty * 4];
            float4 b = *(const float4*)&Bs[k][tx * 4];
            float av[4] = {a.x, a.y, a.z, a.w};
            float bv[4] = {b.x, b.y, b.z, b.w};
            #pragma unroll
            for (int i = 0; i < 4; i++)
                #pragma unroll
                for (int j = 0; j < 4; j++)
                    acc[i][j] += av[i] * bv[j];
        }
        __syncthreads();
    }
    #pragma unroll
    for (int i = 0; i < 4; i++) {
        int row = bm + ty * 4 + i;
        if (row < M) {
            float4 v = make_float4(acc[i][0], acc[i][1], acc[i][2], acc[i][3]);
            *(float4*)(C + (size_t)row * NHID + bn + tx * 4) = v;
        }
    }
}

// ---------------- CSR build ----------------
__global__ void hist_kernel(const int* __restrict__ rows, int* __restrict__ counts, int n)
{
    int i = blockIdx.x * blockDim.x + threadIdx.x;
    int stride = gridDim.x * blockDim.x;
    for (; i < n; i += stride) atomicAdd(&counts[rows[i]], 1);
}

__global__ __launch_bounds__(1024)
void scan_kernel(const int* __restrict__ counts, int* __restrict__ row_ptr,
                 int* __restrict__ cursor, int n)
{
    __shared__ int wsum[16];
    __shared__ int carry_s;
    const int t    = threadIdx.x;
    const int lane = t & 63;
    const int w    = t >> 6;
    if (t == 0) carry_s = 0;
    __syncthreads();
    for (int base = 0; base < n; base += 1024) {
        int c = carry_s;
        int v = (base + t < n) ? counts[base + t] : 0;
        // wave-level inclusive scan (no barriers)
        int x = v;
        #pragma unroll
        for (int off = 1; off < 64; off <<= 1) {
            int y = __shfl_up(x, off);
            if (lane >= off) x += y;
        }
        if (lane == 63) wsum[w] = x;
        __syncthreads();
        if (w == 0) {
            int s = (lane < 16) ? wsum[lane] : 0;
            #pragma unroll
            for (int off = 1; off < 16; off <<= 1) {
                int y = __shfl_up(s, off);
                if (lane >= off) s += y;
            }
            if (lane < 16) wsum[lane] = s;
        }
        __syncthreads();
        int woff = (w > 0) ? wsum[w - 1] : 0;
        int incl = x + woff;
        if (base + t < n) {
            int excl = incl - v + c;
            row_ptr[base + t] = excl;
            cursor[base + t]  = excl;
        }
        int total = wsum[15];
        __syncthreads();
        if (t == 0) carry_s = c + total;
        __syncthreads();
    }
    if (t == 0) row_ptr[n] = carry_s;
}

__global__ void scatter_edges_kernel(const int* __restrict__ rows, const int* __restrict__ cols,
                                     const float* __restrict__ vals, int* __restrict__ cursor,
                                     int* __restrict__ col_s, float* __restrict__ val_s, int n)
{
    int i = blockIdx.x * blockDim.x + threadIdx.x;
    int stride = gridDim.x * blockDim.x;
    for (; i < n; i += stride) {
        int r = rows[i];
        int p = atomicAdd(&cursor[r], 1);
        col_s[p] = cols[i];
        val_s[p] = vals[i];
    }
}

// ---------------- SpMM + bias + ReLU: out[r] = relu(sum_e val_e * support[col_e] + b) ----------------
__global__ __launch_bounds__(256)
void spmm_relu_kernel(const int* __restrict__ row_ptr, const int* __restrict__ col_s,
                      const float* __restrict__ val_s, const float* __restrict__ support,
                      const float* __restrict__ bias, float* __restrict__ out)
{
    __shared__ int   s_col[256];
    __shared__ float s_val[256];
    const int r = blockIdx.x;
    const int t = threadIdx.x;
    const int start = row_ptr[r];
    const int end   = row_ptr[r + 1];
    float a0 = 0.f, a1 = 0.f, a2 = 0.f, a3 = 0.f;
    for (int base = start; base < end; base += 256) {
        int j = base + t;
        if (j < end) { s_col[t] = col_s[j]; s_val[t] = val_s[j]; }
        __syncthreads();
        int cnt = min(256, end - base);
        int i = 0;
        for (; i + 4 <= cnt; i += 4) {
            a0 += s_val[i + 0] * support[(size_t)s_col[i + 0] * NHID + t];
            a1 += s_val[i + 1] * support[(size_t)s_col[i + 1] * NHID + t];
            a2 += s_val[i + 2] * support[(size_t)s_col[i + 2] * NHID + t];
            a3 += s_val[i + 3] * support[(size_t)s_col[i + 3] * NHID + t];
        }
        for (; i < cnt; i++)
            a0 += s_val[i] * support[(size_t)s_col[i] * NHID + t];
        __syncthreads();
    }
    float acc = (a0 + a1) + (a2 + a3) + bias[t];
    out[(size_t)r * NHID + t] = fmaxf(acc, 0.f);
}

// ---------------- Final scatter: out[pos_idx[i]] = h[i] ----------------
__global__ __launch_bounds__(256)
void scatter_out_kernel(const float* __restrict__ h, const int* __restrict__ pos_idx,
                        float* __restrict__ out)
{
    int i = blockIdx.x;
    int t = threadIdx.x;
    out[(size_t)pos_idx[i] * NHID + t] = h[(size_t)i * NHID + t];
}

extern "C" void kernel_launch(void* const* d_in, const int* in_sizes, int n_in,
                              void* d_out, int out_size, void* d_ws, size_t ws_size,
                              hipStream_t stream)
{
    const float* x     = (const float*)d_in[0];
    const float* motif = (const float*)d_in[1];
    const int*   rows  = (const int*)d_in[2];
    const int*   cols  = (const int*)d_in[3];
    const float* vals  = (const float*)d_in[4];
    const int*   pos   = (const int*)d_in[5];
    // d_in[6] = pad_n scalar (65536), implicit in out_size
    const float* w1 = (const float*)d_in[7];
    const float* b1 = (const float*)d_in[8];
    const float* w2 = (const float*)d_in[9];
    const float* b2 = (const float*)d_in[10];
    const float* w3 = (const float*)d_in[11];
    const float* b3 = (const float*)d_in[12];

    char* ws = (char*)d_ws;
    size_t off = 0;
    float* h       = (float*)(ws + off); off += (size_t)N_TOTAL * NHID * 4;  // 61.44 MB
    float* support = (float*)(ws + off); off += (size_t)N_TOTAL * NHID * 4;  // 61.44 MB
    int*   row_ptr = (int*)(ws + off);   off += ((size_t)N_TOTAL + 64) * 4;
    int*   cursor  = (int*)(ws + off);   off += (size_t)(N_TOTAL + 64) * 4;
    int*   counts  = (int*)(ws + off);   off += (size_t)(N_TOTAL + 64) * 4;
    int*   col_s   = (int*)(ws + off);   off += (size_t)N_EDGE * 4;          // 7.68 MB
    float* val_s   = (float*)(ws + off); off += (size_t)N_EDGE * 4;          // 7.68 MB
    (void)ws_size; (void)n_in; (void)in_sizes;

    // --- CSR build (graph identical across the 3 layers; build once per launch) ---
    hipMemsetAsync(counts, 0, (size_t)N_TOTAL * 4, stream);
    hist_kernel<<<2048, 256, 0, stream>>>(rows, counts, N_EDGE);
    scan_kernel<<<1, 1024, 0, stream>>>(counts, row_ptr, cursor, N_TOTAL);
    scatter_edges_kernel<<<2048, 256, 0, stream>>>(rows, cols, vals, cursor, col_s, val_s, N_EDGE);

    dim3 gemm_grid((N_TOTAL + BM - 1) / BM, NHID / BN);

    // layer 1: support = concat(x, motif) @ w1 ; h = relu(A·support + b1)
    gemm_kernel<<<gemm_grid, 256, 0, stream>>>(x, motif, N_X, w1, support, N_TOTAL, NFEAT);
    spmm_relu_kernel<<<N_TOTAL, 256, 0, stream>>>(row_ptr, col_s, val_s, support, b1, h);
    // layer 2
    gemm_kernel<<<gemm_grid, 256, 0, stream>>>(h, h, N_TOTAL + 1, w2, support, N_TOTAL, NHID);
    spmm_relu_kernel<<<N_TOTAL, 256, 0, stream>>>(row_ptr, col_s, val_s, support, b2, h);
    // layer 3
    gemm_kernel<<<gemm_grid, 256, 0, stream>>>(h, h, N_TOTAL + 1, w3, support, N_TOTAL, NHID);
    spmm_relu_kernel<<<N_TOTAL, 256, 0, stream>>>(row_ptr, col_s, val_s, support, b3, h);

    // output: zero 65536x256 then scatter first 50000 rows of h via pos_idx
    hipMemsetAsync(d_out, 0, (size_t)out_size * sizeof(float), stream);
    scatter_out_kernel<<<N_X, 256, 0, stream>>>(h, pos, (float*)d_out);
}

// Round 2
// 923.676 us; speedup vs baseline: 1.7461x; 1.7461x over previous
//
#include <hip/hip_runtime.h>

#define N_TOTAL 60000
#define N_X     50000
#define N_EDGE  1920000
#define NFEAT   512
#define NHID    256

typedef __attribute__((ext_vector_type(8))) short bf16x8;
typedef __attribute__((ext_vector_type(4))) float f32x4;

__device__ __forceinline__ unsigned short f2bf(float f) {
    unsigned u = __float_as_uint(f);
    unsigned r = (u + 0x7FFFu + ((u >> 16) & 1u)) >> 16;   // RNE
    return (unsigned short)r;
}

// ---------------- fp32 -> bf16 elementwise convert (vectorized) ----------------
__global__ __launch_bounds__(256)
void cvt_kernel(const float4* __restrict__ src, ushort4* __restrict__ dst, int n4)
{
    int i = blockIdx.x * blockDim.x + threadIdx.x;
    if (i < n4) {
        float4 v = src[i];
        ushort4 o;
        o.x = f2bf(v.x); o.y = f2bf(v.y); o.z = f2bf(v.z); o.w = f2bf(v.w);
        dst[i] = o;
    }
}

// ---------------- W[K][256] fp32 -> WT[256][K] bf16 (tiny, once per launch) ----------------
__global__ __launch_bounds__(256)
void cvt_w_kernel(const float* __restrict__ w, short* __restrict__ wt, int K)
{
    int n = blockIdx.x;                 // output row (0..255)
    for (int k = threadIdx.x; k < K; k += 256)
        wt[(size_t)n * K + k] = (short)f2bf(w[(size_t)k * NHID + n]);
}

// ---------------- bf16 MFMA GEMM: C[M x 256] = A[M x K] @ BT[256 x K]^T ----------------
#define LDA 40   // padded LDS row stride (elements): 80B -> 2-way bank alias only (free)

__global__ __launch_bounds__(256)
void gemm_bt_kernel(const short* __restrict__ A, const short* __restrict__ BT,
                    short* __restrict__ C, int M, int K)
{
    __shared__ short As[128 * LDA];
    __shared__ short Bs[128 * LDA];
    const int t    = threadIdx.x;
    const int lane = t & 63;
    const int wave = t >> 6;
    const int wm   = wave & 1;
    const int wn   = wave >> 1;
    const int l16  = lane & 15;
    const int quad = lane >> 4;
    const int bm   = blockIdx.x * 128;
    const int bn   = blockIdx.y * 128;

    f32x4 acc[4][4] = {};

    const int srow = t >> 2;     // 0..63
    const int sch  = t & 3;      // chunk of 8 bf16

    for (int kk = 0; kk < K; kk += 32) {
        // stage A tile (128 x 32) and B tile (128 x 32), 2 rows per thread each
        bf16x8 va0 = {}, va1 = {};
        int r0 = bm + srow, r1 = bm + srow + 64;
        if (r0 < M) va0 = *(const bf16x8*)(A + (size_t)r0 * K + kk + sch * 8);
        if (r1 < M) va1 = *(const bf16x8*)(A + (size_t)r1 * K + kk + sch * 8);
        bf16x8 vb0 = *(const bf16x8*)(BT + (size_t)(bn + srow) * K + kk + sch * 8);
        bf16x8 vb1 = *(const bf16x8*)(BT + (size_t)(bn + srow + 64) * K + kk + sch * 8);
        *(bf16x8*)&As[srow * LDA + sch * 8]        = va0;
        *(bf16x8*)&As[(srow + 64) * LDA + sch * 8] = va1;
        *(bf16x8*)&Bs[srow * LDA + sch * 8]        = vb0;
        *(bf16x8*)&Bs[(srow + 64) * LDA + sch * 8] = vb1;
        __syncthreads();

        bf16x8 af[4], bfr[4];
        #pragma unroll
        for (int i = 0; i < 4; i++) {
            af[i]  = *(const bf16x8*)&As[(wm * 64 + i * 16 + l16) * LDA + quad * 8];
            bfr[i] = *(const bf16x8*)&Bs[(wn * 64 + i * 16 + l16) * LDA + quad * 8];
        }
        #pragma unroll
        for (int i = 0; i < 4; i++)
            #pragma unroll
            for (int j = 0; j < 4; j++)
                acc[i][j] = __builtin_amdgcn_mfma_f32_16x16x32_bf16(af[i], bfr[j], acc[i][j], 0, 0, 0);
        __syncthreads();
    }

    // epilogue: C/D layout col = lane&15, row = quad*4 + reg
    #pragma unroll
    for (int i = 0; i < 4; i++) {
        #pragma unroll
        for (int r = 0; r < 4; r++) {
            int row = bm + wm * 64 + i * 16 + quad * 4 + r;
            if (row < M) {
                #pragma unroll
                for (int j = 0; j < 4; j++) {
                    int col = bn + wn * 64 + j * 16 + l16;
                    C[(size_t)row * NHID + col] = (short)f2bf(acc[i][j][r]);
                }
            }
        }
    }
}

// ---------------- CSR build ----------------
__global__ void hist_kernel(const int* __restrict__ rows, int* __restrict__ counts, int n)
{
    int i = blockIdx.x * blockDim.x + threadIdx.x;
    int stride = gridDim.x * blockDim.x;
    for (; i < n; i += stride) atomicAdd(&counts[rows[i]], 1);
}

// local exclusive scan of 1024 elements per block; writes local excl into row_ptr, block totals
__global__ __launch_bounds__(1024)
void block_scan_kernel(const int* __restrict__ counts, int* __restrict__ row_ptr,
                       int* __restrict__ blk_sums, int n)
{
    __shared__ int wsum[16];
    const int t    = threadIdx.x;
    const int lane = t & 63;
    const int w    = t >> 6;
    const int i    = blockIdx.x * 1024 + t;
    int v = (i < n) ? counts[i] : 0;
    int x = v;
    #pragma unroll
    for (int off = 1; off < 64; off <<= 1) {
        int y = __shfl_up(x, off);
        if (lane >= off) x += y;
    }
    if (lane == 63) wsum[w] = x;
    __syncthreads();
    if (w == 0) {
        int s = (lane < 16) ? wsum[lane] : 0;
        #pragma unroll
        for (int off = 1; off < 16; off <<= 1) {
            int y = __shfl_up(s, off);
            if (lane >= off) s += y;
        }
        if (lane < 16) wsum[lane] = s;
    }
    __syncthreads();
    int woff = (w > 0) ? wsum[w - 1] : 0;
    if (i < n) row_ptr[i] = x + woff - v;     // local exclusive
    if (t == 1023) blk_sums[blockIdx.x] = x + woff;
}

__global__ __launch_bounds__(64)
void scan_sums_kernel(int* __restrict__ blk_sums, int* __restrict__ blk_off,
                      int* __restrict__ row_ptr, int nblk, int n)
{
    int t = threadIdx.x;
    int v = (t < nblk) ? blk_sums[t] : 0;
    int x = v;
    #pragma unroll
    for (int off = 1; off < 64; off <<= 1) {
        int y = __shfl_up(x, off);
        if (t >= off) x += y;
    }
    if (t < nblk) blk_off[t] = x - v;
    if (t == 63) row_ptr[n] = x;   // grand total
}

__global__ __launch_bounds__(1024)
void add_off_kernel(int* __restrict__ row_ptr, int* __restrict__ cursor,
                    const int* __restrict__ blk_off, int n)
{
    int i = blockIdx.x * 1024 + threadIdx.x;
    if (i < n) {
        int v = row_ptr[i] + blk_off[blockIdx.x];
        row_ptr[i] = v;
        cursor[i]  = v;
    }
}

__global__ void scatter_edges_kernel(const int* __restrict__ rows, const int* __restrict__ cols,
                                     const float* __restrict__ vals, int* __restrict__ cursor,
                                     int* __restrict__ col_s, float* __restrict__ val_s, int n)
{
    int i = blockIdx.x * blockDim.x + threadIdx.x;
    int stride = gridDim.x * blockDim.x;
    for (; i < n; i += stride) {
        int r = rows[i];
        int p = atomicAdd(&cursor[r], 1);
        col_s[p] = cols[i];
        val_s[p] = vals[i];
    }
}

// ---------------- SpMM + bias + ReLU over bf16 support ----------------
// 128 threads/row; thread t handles features {2t, 2t+1} as one packed u32 (2 bf16).
__global__ __launch_bounds__(128)
void spmm_relu_kernel(const int* __restrict__ row_ptr, const int* __restrict__ col_s,
                      const float* __restrict__ val_s, const unsigned* __restrict__ support,
                      const float* __restrict__ bias, unsigned* __restrict__ out_bf,
                      float* __restrict__ out_f32, int write_f32)
{
    __shared__ int   s_col[128];
    __shared__ float s_val[128];
    const int r = blockIdx.x;
    const int t = threadIdx.x;
    const int start = row_ptr[r];
    const int end   = row_ptr[r + 1];
    float2 a0 = {0.f, 0.f}, a1 = {0.f, 0.f}, a2 = {0.f, 0.f}, a3 = {0.f, 0.f};
    for (int base = start; base < end; base += 128) {
        int j = base + t;
        if (j < end) { s_col[t] = col_s[j]; s_val[t] = val_s[j]; }
        __syncthreads();
        int cnt = min(128, end - base);
        int i = 0;
        for (; i + 4 <= cnt; i += 4) {
            unsigned u0 = support[(size_t)s_col[i + 0] * 128 + t];
            unsigned u1 = support[(size_t)s_col[i + 1] * 128 + t];
            unsigned u2 = support[(size_t)s_col[i + 2] * 128 + t];
            unsigned u3 = support[(size_t)s_col[i + 3] * 128 + t];
            float v0 = s_val[i + 0], v1 = s_val[i + 1], v2 = s_val[i + 2], v3 = s_val[i + 3];
            a0.x += v0 * __uint_as_float(u0 << 16);
            a0.y += v0 * __uint_as_float(u0 & 0xFFFF0000u);
            a1.x += v1 * __uint_as_float(u1 << 16);
            a1.y += v1 * __uint_as_float(u1 & 0xFFFF0000u);
            a2.x += v2 * __uint_as_float(u2 << 16);
            a2.y += v2 * __uint_as_float(u2 & 0xFFFF0000u);
            a3.x += v3 * __uint_as_float(u3 << 16);
            a3.y += v3 * __uint_as_float(u3 & 0xFFFF0000u);
        }
        for (; i < cnt; i++) {
            unsigned u = support[(size_t)s_col[i] * 128 + t];
            float v = s_val[i];
            a0.x += v * __uint_as_float(u << 16);
            a0.y += v * __uint_as_float(u & 0xFFFF0000u);
        }
        __syncthreads();
    }
    float2 b = ((const float2*)bias)[t];
    float rx = fmaxf((a0.x + a1.x) + (a2.x + a3.x) + b.x, 0.f);
    float ry = fmaxf((a0.y + a1.y) + (a2.y + a3.y) + b.y, 0.f);
    if (write_f32) {
        float2 o = {rx, ry};
        ((float2*)out_f32)[(size_t)r * 128 + t] = o;
    } else {
        unsigned lo = f2bf(rx), hi = f2bf(ry);
        out_bf[(size_t)r * 128 + t] = lo | (hi << 16);
    }
}

// ---------------- Final scatter: out[pos_idx[i]] = h[i] (float4) ----------------
__global__ __launch_bounds__(64)
void scatter_out_kernel(const float4* __restrict__ h, const int* __restrict__ pos_idx,
                        float4* __restrict__ out)
{
    int i = blockIdx.x;
    int t = threadIdx.x;
    out[(size_t)pos_idx[i] * 64 + t] = h[(size_t)i * 64 + t];
}

extern "C" void kernel_launch(void* const* d_in, const int* in_sizes, int n_in,
                              void* d_out, int out_size, void* d_ws, size_t ws_size,
                              hipStream_t stream)
{
    const float* x     = (const float*)d_in[0];
    const float* motif = (const float*)d_in[1];
    const int*   rows  = (const int*)d_in[2];
    const int*   cols  = (const int*)d_in[3];
    const float* vals  = (const float*)d_in[4];
    const int*   pos   = (const int*)d_in[5];
    const float* w1 = (const float*)d_in[7];
    const float* b1 = (const float*)d_in[8];
    const float* w2 = (const float*)d_in[9];
    const float* b2 = (const float*)d_in[10];
    const float* w3 = (const float*)d_in[11];
    const float* b3 = (const float*)d_in[12];
    (void)ws_size; (void)n_in; (void)in_sizes;

    char* ws = (char*)d_ws;
    size_t off = 0;
    short* h_bf    = (short*)(ws + off); off += (size_t)N_TOTAL * NFEAT * 2;   // 61.44 MB (also aliased as h_f32)
    short* support = (short*)(ws + off); off += (size_t)N_TOTAL * NHID * 2;    // 30.72 MB
    short* w1T     = (short*)(ws + off); off += (size_t)NHID * NFEAT * 2;
    short* w2T     = (short*)(ws + off); off += (size_t)NHID * NHID * 2;
    short* w3T     = (short*)(ws + off); off += (size_t)NHID * NHID * 2;
    int* row_ptr   = (int*)(ws + off);   off += 60064 * 4;
    int* cursor    = (int*)(ws + off);   off += 60064 * 4;
    int* counts    = (int*)(ws + off);   off += 60064 * 4;
    int* blk_sums  = (int*)(ws + off);   off += 64 * 4;
    int* blk_off   = (int*)(ws + off);   off += 64 * 4;
    int* col_s     = (int*)(ws + off);   off += (size_t)N_EDGE * 4;
    float* val_s   = (float*)(ws + off); off += (size_t)N_EDGE * 4;
    float* h_f32   = (float*)h_bf;   // layer-3 output aliases h_bf (h_bf dead by then)

    // --- bf16 conversions ---
    cvt_kernel<<<(N_X * NFEAT / 4 + 255) / 256, 256, 0, stream>>>(
        (const float4*)x, (ushort4*)h_bf, N_X * NFEAT / 4);
    cvt_kernel<<<((N_TOTAL - N_X) * NFEAT / 4 + 255) / 256, 256, 0, stream>>>(
        (const float4*)motif, (ushort4*)(h_bf + (size_t)N_X * NFEAT), (N_TOTAL - N_X) * NFEAT / 4);
    cvt_w_kernel<<<NHID, 256, 0, stream>>>(w1, w1T, NFEAT);
    cvt_w_kernel<<<NHID, 256, 0, stream>>>(w2, w2T, NHID);
    cvt_w_kernel<<<NHID, 256, 0, stream>>>(w3, w3T, NHID);

    // --- CSR build ---
    hipMemsetAsync(counts, 0, (size_t)N_TOTAL * 4, stream);
    hist_kernel<<<2048, 256, 0, stream>>>(rows, counts, N_EDGE);
    const int nblk = (N_TOTAL + 1023) / 1024;   // 59
    block_scan_kernel<<<nblk, 1024, 0, stream>>>(counts, row_ptr, blk_sums, N_TOTAL);
    scan_sums_kernel<<<1, 64, 0, stream>>>(blk_sums, blk_off, row_ptr, nblk, N_TOTAL);
    add_off_kernel<<<nblk, 1024, 0, stream>>>(row_ptr, cursor, blk_off, N_TOTAL);
    scatter_edges_kernel<<<2048, 256, 0, stream>>>(rows, cols, vals, cursor, col_s, val_s, N_EDGE);

    dim3 ggrid((N_TOTAL + 127) / 128, NHID / 128);

    // layer 1
    gemm_bt_kernel<<<ggrid, 256, 0, stream>>>(h_bf, w1T, support, N_TOTAL, NFEAT);
    spmm_relu_kernel<<<N_TOTAL, 128, 0, stream>>>(row_ptr, col_s, val_s, (const unsigned*)support,
                                                  b1, (unsigned*)h_bf, nullptr, 0);
    // layer 2
    gemm_bt_kernel<<<ggrid, 256, 0, stream>>>(h_bf, w2T, support, N_TOTAL, NHID);
    spmm_relu_kernel<<<N_TOTAL, 128, 0, stream>>>(row_ptr, col_s, val_s, (const unsigned*)support,
                                                  b2, (unsigned*)h_bf, nullptr, 0);
    // layer 3 (fp32 output for final scatter)
    gemm_bt_kernel<<<ggrid, 256, 0, stream>>>(h_bf, w3T, support, N_TOTAL, NHID);
    spmm_relu_kernel<<<N_TOTAL, 128, 0, stream>>>(row_ptr, col_s, val_s, (const unsigned*)support,
                                                  b3, nullptr, h_f32, 1);

    // output: zero 65536x256 fp32, scatter first 50000 rows
    hipMemsetAsync(d_out, 0, (size_t)out_size * sizeof(float), stream);
    scatter_out_kernel<<<N_X, 64, 0, stream>>>((const float4*)h_f32, pos, (float4*)d_out);
}

// Round 3
// 868.823 us; speedup vs baseline: 1.8563x; 1.0631x over previous
//
#include <hip/hip_runtime.h>

#define N_TOTAL 60000
#define N_X     50000
#define N_EDGE  1920000
#define NFEAT   512
#define NHID    256

typedef __attribute__((ext_vector_type(8))) short bf16x8;
typedef __attribute__((ext_vector_type(4))) float f32x4;

__device__ __forceinline__ unsigned short f2bf(float f) {
    unsigned u = __float_as_uint(f);
    unsigned r = (u + 0x7FFFu + ((u >> 16) & 1u)) >> 16;   // RNE
    return (unsigned short)r;
}
__device__ __forceinline__ float bf_lo(unsigned u) { return __uint_as_float(u << 16); }
__device__ __forceinline__ float bf_hi(unsigned u) { return __uint_as_float(u & 0xFFFF0000u); }

// ---------------- W[K][256] fp32 -> WT[256][K] bf16 (tiny, once per launch) ----------------
__global__ __launch_bounds__(256)
void cvt_w_kernel(const float* __restrict__ w, short* __restrict__ wt, int K)
{
    int n = blockIdx.x;                 // output row (0..255)
    for (int k = threadIdx.x; k < K; k += 256)
        wt[(size_t)n * K + k] = (short)f2bf(w[(size_t)k * NHID + n]);
}

// ---------------- bf16 MFMA GEMM: C[M x 256] = A[M x K] @ BT[256 x K]^T ----------------
// AF32 path: A is fp32 (possibly split across two buffers), converted to bf16 during staging.
#define LDA 40   // padded LDS row stride (shorts): 80B -> 2-way bank alias only (free)

template<bool AF32>
__global__ __launch_bounds__(256)
void gemm_bt_kernel(const float* __restrict__ Af, const float* __restrict__ A2f, int split,
                    const short* __restrict__ Ab, const short* __restrict__ BT,
                    short* __restrict__ C, int M, int K)
{
    __shared__ short As[128 * LDA];
    __shared__ short Bs[128 * LDA];
    const int t    = threadIdx.x;
    const int lane = t & 63;
    const int wave = t >> 6;
    const int wm   = wave & 1;
    const int wn   = wave >> 1;
    const int l16  = lane & 15;
    const int quad = lane >> 4;
    const int bm   = blockIdx.x * 128;
    const int bn   = blockIdx.y * 128;

    f32x4 acc[4][4] = {};

    const int srow = t >> 2;     // 0..63   (bf16 staging)
    const int sch  = t & 3;
    const int frow = t >> 1;     // 0..127  (fp32 staging)
    const int fh   = t & 1;      // k-half (16 floats each)

    for (int kk = 0; kk < K; kk += 32) {
        if (AF32) {
            int row = bm + frow;
            float4 v0 = {}, v1 = {}, v2 = {}, v3 = {};
            if (row < M) {
                const float* src = (row < split) ? (Af + (size_t)row * K)
                                                 : (A2f + (size_t)(row - split) * K);
                const float4* p = (const float4*)(src + kk + fh * 16);
                v0 = p[0]; v1 = p[1]; v2 = p[2]; v3 = p[3];
            }
            short* dst = &As[frow * LDA + fh * 16];
            short tmp[16] = {
                (short)f2bf(v0.x), (short)f2bf(v0.y), (short)f2bf(v0.z), (short)f2bf(v0.w),
                (short)f2bf(v1.x), (short)f2bf(v1.y), (short)f2bf(v1.z), (short)f2bf(v1.w),
                (short)f2bf(v2.x), (short)f2bf(v2.y), (short)f2bf(v2.z), (short)f2bf(v2.w),
                (short)f2bf(v3.x), (short)f2bf(v3.y), (short)f2bf(v3.z), (short)f2bf(v3.w)};
            *(bf16x8*)(dst)     = *(const bf16x8*)&tmp[0];
            *(bf16x8*)(dst + 8) = *(const bf16x8*)&tmp[8];
        } else {
            bf16x8 va0 = {}, va1 = {};
            int r0 = bm + srow, r1 = bm + srow + 64;
            if (r0 < M) va0 = *(const bf16x8*)(Ab + (size_t)r0 * K + kk + sch * 8);
            if (r1 < M) va1 = *(const bf16x8*)(Ab + (size_t)r1 * K + kk + sch * 8);
            *(bf16x8*)&As[srow * LDA + sch * 8]        = va0;
            *(bf16x8*)&As[(srow + 64) * LDA + sch * 8] = va1;
        }
        {
            bf16x8 vb0 = *(const bf16x8*)(BT + (size_t)(bn + srow) * K + kk + sch * 8);
            bf16x8 vb1 = *(const bf16x8*)(BT + (size_t)(bn + srow + 64) * K + kk + sch * 8);
            *(bf16x8*)&Bs[srow * LDA + sch * 8]        = vb0;
            *(bf16x8*)&Bs[(srow + 64) * LDA + sch * 8] = vb1;
        }
        __syncthreads();

        bf16x8 af[4], bfr[4];
        #pragma unroll
        for (int i = 0; i < 4; i++) {
            af[i]  = *(const bf16x8*)&As[(wm * 64 + i * 16 + l16) * LDA + quad * 8];
            bfr[i] = *(const bf16x8*)&Bs[(wn * 64 + i * 16 + l16) * LDA + quad * 8];
        }
        #pragma unroll
        for (int i = 0; i < 4; i++)
            #pragma unroll
            for (int j = 0; j < 4; j++)
                acc[i][j] = __builtin_amdgcn_mfma_f32_16x16x32_bf16(af[i], bfr[j], acc[i][j], 0, 0, 0);
        __syncthreads();
    }

    // epilogue: C/D layout col = lane&15, row = quad*4 + reg
    #pragma unroll
    for (int i = 0; i < 4; i++) {
        #pragma unroll
        for (int r = 0; r < 4; r++) {
            int row = bm + wm * 64 + i * 16 + quad * 4 + r;
            if (row < M) {
                #pragma unroll
                for (int j = 0; j < 4; j++) {
                    int col = bn + wn * 64 + j * 16 + l16;
                    C[(size_t)row * NHID + col] = (short)f2bf(acc[i][j][r]);
                }
            }
        }
    }
}

// ---------------- CSR build ----------------
__global__ __launch_bounds__(256)
void hist_kernel(const int* __restrict__ rows, int* __restrict__ counts, int n)
{
    int i = blockIdx.x * 256 + threadIdx.x;
    if (i < n) atomicAdd(&counts[rows[i]], 1);
}

__global__ __launch_bounds__(1024)
void block_scan_kernel(const int* __restrict__ counts, int* __restrict__ row_ptr,
                       int* __restrict__ blk_sums, int n)
{
    __shared__ int wsum[16];
    const int t    = threadIdx.x;
    const int lane = t & 63;
    const int w    = t >> 6;
    const int i    = blockIdx.x * 1024 + t;
    int v = (i < n) ? counts[i] : 0;
    int x = v;
    #pragma unroll
    for (int off = 1; off < 64; off <<= 1) {
        int y = __shfl_up(x, off);
        if (lane >= off) x += y;
    }
    if (lane == 63) wsum[w] = x;
    __syncthreads();
    if (w == 0) {
        int s = (lane < 16) ? wsum[lane] : 0;
        #pragma unroll
        for (int off = 1; off < 16; off <<= 1) {
            int y = __shfl_up(s, off);
            if (lane >= off) s += y;
        }
        if (lane < 16) wsum[lane] = s;
    }
    __syncthreads();
    int woff = (w > 0) ? wsum[w - 1] : 0;
    if (i < n) row_ptr[i] = x + woff - v;     // local exclusive
    if (t == 1023) blk_sums[blockIdx.x] = x + woff;
}

__global__ __launch_bounds__(64)
void scan_sums_kernel(int* __restrict__ blk_sums, int* __restrict__ blk_off,
                      int* __restrict__ row_ptr, int nblk, int n)
{
    int t = threadIdx.x;
    int v = (t < nblk) ? blk_sums[t] : 0;
    int x = v;
    #pragma unroll
    for (int off = 1; off < 64; off <<= 1) {
        int y = __shfl_up(x, off);
        if (t >= off) x += y;
    }
    if (t < nblk) blk_off[t] = x - v;
    if (t == 63) row_ptr[n] = x;   // grand total
}

__global__ __launch_bounds__(1024)
void add_off_kernel(int* __restrict__ row_ptr, int* __restrict__ cursor,
                    const int* __restrict__ blk_off, int n)
{
    int i = blockIdx.x * 1024 + threadIdx.x;
    if (i < n) {
        int v = row_ptr[i] + blk_off[blockIdx.x];
        row_ptr[i] = v;
        cursor[i]  = v;
    }
}

// packed edge record: low 16 = col (N_TOTAL < 65536), high 16 = val as bf16
__global__ __launch_bounds__(256)
void scatter_edges_kernel(const int* __restrict__ rows, const int* __restrict__ cols,
                          const float* __restrict__ vals, int* __restrict__ cursor,
                          unsigned* __restrict__ edges, int n)
{
    int i = blockIdx.x * 256 + threadIdx.x;
    if (i < n) {
        int r = rows[i];
        unsigned rec = (unsigned)cols[i] | ((unsigned)f2bf(vals[i]) << 16);
        int p = atomicAdd(&cursor[r], 1);
        edges[p] = rec;
    }
}

// ---------------- SpMM + bias + ReLU over bf16 support ----------------
// One wave per row; lane t handles features 4t..4t+3 (uint2 = 4 bf16).
// MODE 0: write bf16 h (packed uint2). MODE 1: write fp32 float4 scattered via pos.
template<int MODE>
__global__ __launch_bounds__(64)
void spmm_relu_kernel(const int* __restrict__ row_ptr, const unsigned* __restrict__ edges,
                      const uint2* __restrict__ support, const float* __restrict__ bias,
                      uint2* __restrict__ out_bf, float* __restrict__ out_f32,
                      const int* __restrict__ pos)
{
    __shared__ unsigned s_edge[64];
    const int r = blockIdx.x;
    const int t = threadIdx.x;
    const int start = row_ptr[r];
    const int end   = row_ptr[r + 1];
    float4 a0 = {}, a1 = {}, a2 = {}, a3 = {};
    for (int base = start; base < end; base += 64) {
        int j = base + t;
        if (j < end) s_edge[t] = edges[j];
        __syncthreads();
        int cnt = min(64, end - base);
        int i = 0;
        for (; i + 4 <= cnt; i += 4) {
            unsigned e0 = s_edge[i + 0], e1 = s_edge[i + 1], e2 = s_edge[i + 2], e3 = s_edge[i + 3];
            uint2 s0 = support[(size_t)(e0 & 0xFFFFu) * 64 + t];
            uint2 s1 = support[(size_t)(e1 & 0xFFFFu) * 64 + t];
            uint2 s2 = support[(size_t)(e2 & 0xFFFFu) * 64 + t];
            uint2 s3 = support[(size_t)(e3 & 0xFFFFu) * 64 + t];
            float v0 = bf_hi(e0), v1 = bf_hi(e1), v2 = bf_hi(e2), v3 = bf_hi(e3);
            a0.x += v0 * bf_lo(s0.x); a0.y += v0 * bf_hi(s0.x); a0.z += v0 * bf_lo(s0.y); a0.w += v0 * bf_hi(s0.y);
            a1.x += v1 * bf_lo(s1.x); a1.y += v1 * bf_hi(s1.x); a1.z += v1 * bf_lo(s1.y); a1.w += v1 * bf_hi(s1.y);
            a2.x += v2 * bf_lo(s2.x); a2.y += v2 * bf_hi(s2.x); a2.z += v2 * bf_lo(s2.y); a2.w += v2 * bf_hi(s2.y);
            a3.x += v3 * bf_lo(s3.x); a3.y += v3 * bf_hi(s3.x); a3.z += v3 * bf_lo(s3.y); a3.w += v3 * bf_hi(s3.y);
        }
        for (; i < cnt; i++) {
            unsigned e = s_edge[i];
            uint2 s = support[(size_t)(e & 0xFFFFu) * 64 + t];
            float v = bf_hi(e);
            a0.x += v * bf_lo(s.x); a0.y += v * bf_hi(s.x); a0.z += v * bf_lo(s.y); a0.w += v * bf_hi(s.y);
        }
        __syncthreads();
    }
    float4 b = ((const float4*)bias)[t];
    float rx = fmaxf((a0.x + a1.x) + (a2.x + a3.x) + b.x, 0.f);
    float ry = fmaxf((a0.y + a1.y) + (a2.y + a3.y) + b.y, 0.f);
    float rz = fmaxf((a0.z + a1.z) + (a2.z + a3.z) + b.z, 0.f);
    float rw = fmaxf((a0.w + a1.w) + (a2.w + a3.w) + b.w, 0.f);
    if (MODE == 1) {
        float4 o = {rx, ry, rz, rw};
        ((float4*)out_f32)[(size_t)pos[r] * 64 + t] = o;
    } else {
        uint2 o;
        o.x = (unsigned)f2bf(rx) | ((unsigned)f2bf(ry) << 16);
        o.y = (unsigned)f2bf(rz) | ((unsigned)f2bf(rw) << 16);
        out_bf[(size_t)r * 64 + t] = o;
    }
}

extern "C" void kernel_launch(void* const* d_in, const int* in_sizes, int n_in,
                              void* d_out, int out_size, void* d_ws, size_t ws_size,
                              hipStream_t stream)
{
    const float* x     = (const float*)d_in[0];
    const float* motif = (const float*)d_in[1];
    const int*   rows  = (const int*)d_in[2];
    const int*   cols  = (const int*)d_in[3];
    const float* vals  = (const float*)d_in[4];
    const int*   pos   = (const int*)d_in[5];
    const float* w1 = (const float*)d_in[7];
    const float* b1 = (const float*)d_in[8];
    const float* w2 = (const float*)d_in[9];
    const float* b2 = (const float*)d_in[10];
    const float* w3 = (const float*)d_in[11];
    const float* b3 = (const float*)d_in[12];
    (void)ws_size; (void)n_in; (void)in_sizes;

    char* ws = (char*)d_ws;
    size_t off = 0;
    short* h_bf     = (short*)(ws + off); off += (size_t)N_TOTAL * NHID * 2;    // 30.72 MB
    short* support  = (short*)(ws + off); off += (size_t)N_TOTAL * NHID * 2;    // 30.72 MB
    short* w1T      = (short*)(ws + off); off += (size_t)NHID * NFEAT * 2;
    short* w2T      = (short*)(ws + off); off += (size_t)NHID * NHID * 2;
    short* w3T      = (short*)(ws + off); off += (size_t)NHID * NHID * 2;
    int* row_ptr    = (int*)(ws + off);   off += 60064 * 4;
    int* cursor     = (int*)(ws + off);   off += 60064 * 4;
    int* counts     = (int*)(ws + off);   off += 60064 * 4;
    int* blk_sums   = (int*)(ws + off);   off += 64 * 4;
    int* blk_off    = (int*)(ws + off);   off += 64 * 4;
    unsigned* edges = (unsigned*)(ws + off); off += (size_t)N_EDGE * 4;         // 7.68 MB

    // --- weight conversions (tiny) ---
    cvt_w_kernel<<<NHID, 256, 0, stream>>>(w1, w1T, NFEAT);
    cvt_w_kernel<<<NHID, 256, 0, stream>>>(w2, w2T, NHID);
    cvt_w_kernel<<<NHID, 256, 0, stream>>>(w3, w3T, NHID);

    // --- CSR build ---
    hipMemsetAsync(counts, 0, (size_t)N_TOTAL * 4, stream);
    hist_kernel<<<(N_EDGE + 255) / 256, 256, 0, stream>>>(rows, counts, N_EDGE);
    const int nblk = (N_TOTAL + 1023) / 1024;   // 59
    block_scan_kernel<<<nblk, 1024, 0, stream>>>(counts, row_ptr, blk_sums, N_TOTAL);
    scan_sums_kernel<<<1, 64, 0, stream>>>(blk_sums, blk_off, row_ptr, nblk, N_TOTAL);
    add_off_kernel<<<nblk, 1024, 0, stream>>>(row_ptr, cursor, blk_off, N_TOTAL);
    scatter_edges_kernel<<<(N_EDGE + 255) / 256, 256, 0, stream>>>(rows, cols, vals, cursor, edges, N_EDGE);

    dim3 ggrid((N_TOTAL + 127) / 128, NHID / 128);

    // layer 1: support = concat(x, motif) @ w1 (fp32 A converted in staging)
    gemm_bt_kernel<true><<<ggrid, 256, 0, stream>>>(x, motif, N_X, nullptr, w1T, support, N_TOTAL, NFEAT);
    spmm_relu_kernel<0><<<N_TOTAL, 64, 0, stream>>>(row_ptr, edges, (const uint2*)support, b1,
                                                    (uint2*)h_bf, nullptr, nullptr);
    // layer 2
    gemm_bt_kernel<false><<<ggrid, 256, 0, stream>>>(nullptr, nullptr, 0, h_bf, w2T, support, N_TOTAL, NHID);
    spmm_relu_kernel<0><<<N_TOTAL, 64, 0, stream>>>(row_ptr, edges, (const uint2*)support, b2,
                                                    (uint2*)h_bf, nullptr, nullptr);
    // layer 3: only rows < N_X are needed; scatter fp32 straight into d_out
    gemm_bt_kernel<false><<<ggrid, 256, 0, stream>>>(nullptr, nullptr, 0, h_bf, w3T, support, N_TOTAL, NHID);
    hipMemsetAsync(d_out, 0, (size_t)out_size * sizeof(float), stream);
    spmm_relu_kernel<1><<<N_X, 64, 0, stream>>>(row_ptr, edges, (const uint2*)support, b3,
                                                nullptr, (float*)d_out, pos);
}